// Round 10
// baseline (289.544 us; speedup 1.0000x reference)
//
#include <hip/hip_runtime.h>
#include <hip/hip_bf16.h>

typedef unsigned int u32;
typedef unsigned short u16;
typedef unsigned char u8;
typedef __attribute__((ext_vector_type(8))) short short8;
typedef __attribute__((ext_vector_type(4))) float f32x4;
typedef __attribute__((ext_vector_type(4))) int i32x4;
typedef __attribute__((ext_vector_type(8))) int i32x8;

#define EPSV 1e-5f
#define MAXN (1.0f - 1e-5f)
#define THETA 0.17f
#define CAP 512
#define LCAPW 384u

__device__ __forceinline__ u16 f2bf(float f) {
    union { float f; u32 u; } v; v.f = f;
    u32 u = v.u;
    u32 r = (u + 0x7fffu + ((u >> 16) & 1u)) >> 16;
    return (u16)r;
}
__device__ __forceinline__ float bf2f(u16 h) {
    union { u32 u; float f; } v; v.u = ((u32)h) << 16;
    return v.f;
}
// 4 floats -> 4 OCP e4m3 bytes (gfx950 HW cvt)
__device__ __forceinline__ u32 pk_fp8x4(float a, float b, float c, float d) {
    int v = __builtin_amdgcn_cvt_pk_fp8_f32(a, b, 0, false);
    v = __builtin_amdgcn_cvt_pk_fp8_f32(c, d, v, true);
    return (u32)v;
}
__device__ __forceinline__ u8 f2fp8(float a) {
    return (u8)(__builtin_amdgcn_cvt_pk_fp8_f32(a, a, 0, false) & 0xFF);
}

typedef __attribute__((address_space(1))) const unsigned char gbuf_t;
typedef __attribute__((address_space(3))) unsigned char lbuf_t;
__device__ __forceinline__ void gl2lds16(const void* g, void* l) {
    __builtin_amdgcn_global_load_lds((gbuf_t*)g, (lbuf_t*)l, 16, 0, 0);
}

// ---------------- fused pre: memory project + bf16 + fp8 + hidden->bf16 + transposes ----------------
__global__ __launch_bounds__(256) void k_pre(const float* __restrict__ mem,
                                             u16* __restrict__ mbf,
                                             u8* __restrict__ mbf8,
                                             float* __restrict__ y2m,
                                             u32* __restrict__ cnt,
                                             const float* __restrict__ hidden, u16* __restrict__ hb,
                                             const float* __restrict__ w1, u16* __restrict__ w1t,
                                             const float* __restrict__ w2, u16* __restrict__ w2t,
                                             const float* __restrict__ wp, u16* __restrict__ wpt) {
    __shared__ float ld[64 * 65];
    const int b = blockIdx.x, t = threadIdx.x;
    if (b < 16384) {                      // memory bank: project + bf16 + fp8 + y2
        int zi = b * 256 + t;
        if (zi < 2048) cnt[zi] = 0;
        const int row = b * 4 + (t >> 6);
        const int lane = t & 63;
        const float4* p = (const float4*)(mem + (size_t)row * 256);
        float4 v = p[lane];
        float ss = v.x * v.x + v.y * v.y + v.z * v.z + v.w * v.w;
#pragma unroll
        for (int off = 32; off; off >>= 1) ss += __shfl_xor(ss, off);
        float norm = sqrtf(ss);
        float scale = (norm > MAXN) ? MAXN / fmaxf(norm, EPSV) : 1.0f;
        float x0 = v.x * scale, x1 = v.y * scale, x2 = v.z * scale, x3 = v.w * scale;
        ushort4 u;
        u.x = f2bf(x0); u.y = f2bf(x1); u.z = f2bf(x2); u.w = f2bf(x3);
        *(ushort4*)&mbf[(size_t)row * 256 + lane * 4] = u;
        *(u32*)&mbf8[(size_t)row * 256 + lane * 4] = pk_fp8x4(x0, x1, x2, x3);
        if (lane == 0) y2m[row] = ss * scale * scale;
    } else if (b < 18432) {               // hidden f32 -> bf16
        int i = (b - 16384) * 256 + t;
        float4 v = ((const float4*)hidden)[i];
        ushort4 u; u.x = f2bf(v.x); u.y = f2bf(v.y); u.z = f2bf(v.z); u.w = f2bf(v.w);
        ((ushort4*)hb)[i] = u;
    } else {                              // transpose f32 src[K][N] -> bf16 dst[N][K], 64x64 tiles
        const float* src; u16* dst; int K, N, tile;
        int bb = b - 18432;
        if (bb < 64)      { src = w1; dst = w1t; K = 1024; N = 256;  tile = bb; }
        else if (bb < 80) { src = w2; dst = w2t; K = 256;  N = 256;  tile = bb - 64; }
        else              { src = wp; dst = wpt; K = 256;  N = 1024; tile = bb - 80; }
        int ntn = N >> 6;
        int tk = (tile / ntn) * 64, tn = (tile - (tile / ntn) * ntn) * 64;
#pragma unroll
        for (int j = 0; j < 16; ++j) {
            int lin = j * 256 + t;
            int r = lin >> 6, c = lin & 63;
            ld[r * 65 + c] = src[(size_t)(tk + r) * N + tn + c];
        }
        __syncthreads();
#pragma unroll
        for (int j = 0; j < 16; ++j) {
            int lin = j * 256 + t;
            int c2 = lin >> 6, r2 = lin & 63;
            dst[(size_t)(tn + c2) * K + tk + r2] = f2bf(ld[r2 * 65 + c2]);
        }
    }
}

// ---------------- fused query net: GEMM1 + bias + LN + GELU (LDS) + GEMM2 + bias + project ----
// grid 128, block 256 (4 waves), 16 q-rows per block. Emits fp8 q (for k_dist) + f32 x2q.
__global__ __launch_bounds__(256) void k_qnet(const u16* __restrict__ hb,
                                              const u16* __restrict__ w1t,
                                              const float* __restrict__ b1,
                                              const float* __restrict__ lng,
                                              const float* __restrict__ lnb,
                                              const u16* __restrict__ w2t,
                                              const float* __restrict__ b2,
                                              u8* __restrict__ qb8,
                                              float* __restrict__ x2q) {
    __shared__ float sm[16 * 260];
    __shared__ u16 qs[16 * 264];
    const int t = threadIdx.x;
    const int w = t >> 6, lane = t & 63;
    const int l16 = lane & 15, kq = (lane >> 4) * 8, rbase = (lane >> 4) * 4;
    const int q0 = blockIdx.x * 16;
    f32x4 zero = {0.f, 0.f, 0.f, 0.f};

    // ---- GEMM1: 16 x 256 (K=1024)
    {
        f32x4 acc[4] = {zero, zero, zero, zero};
        const u16* ap = hb + (size_t)(q0 + l16) * 1024 + kq;
        for (int k0 = 0; k0 < 1024; k0 += 32) {
            short8 av = *(const short8*)(ap + k0);
#pragma unroll
            for (int ct = 0; ct < 4; ++ct) {
                int n = w * 64 + ct * 16 + l16;
                short8 bv = *(const short8*)&w1t[(size_t)n * 1024 + k0 + kq];
                acc[ct] = __builtin_amdgcn_mfma_f32_16x16x32_bf16(av, bv, acc[ct], 0, 0, 0);
            }
        }
#pragma unroll
        for (int ct = 0; ct < 4; ++ct) {
            int n = w * 64 + ct * 16 + l16;
            float bias = b1[n];
#pragma unroll
            for (int r = 0; r < 4; ++r)
                sm[(rbase + r) * 260 + n] = acc[ct][r] + bias;
        }
    }
    __syncthreads();
    // ---- LayerNorm + GELU -> qs (bf16 in LDS)
    {
        const int row = t >> 4, sub = t & 15;
        float s1 = 0.f, s2 = 0.f;
#pragma unroll
        for (int i = 0; i < 16; ++i) {
            float v = sm[row * 260 + sub + 16 * i];
            s1 += v; s2 += v * v;
        }
#pragma unroll
        for (int off = 8; off; off >>= 1) {
            s1 += __shfl_xor(s1, off, 16);
            s2 += __shfl_xor(s2, off, 16);
        }
        float mu = s1 * (1.0f / 256.0f);
        float var = s2 * (1.0f / 256.0f) - mu * mu;
        float rstd = rsqrtf(var + EPSV);
#pragma unroll
        for (int i = 0; i < 16; ++i) {
            int cc = sub + 16 * i;
            float v = sm[row * 260 + cc];
            float xn = (v - mu) * rstd * lng[cc] + lnb[cc];
            float ge = 0.5f * xn * (1.0f + erff(xn * 0.7071067811865475f));
            qs[row * 264 + cc] = f2bf(ge);
        }
    }
    __syncthreads();
    // ---- GEMM2: 16 x 256 (K=256), A from LDS qs
    f32x4 acc2[4] = {zero, zero, zero, zero};
    for (int k0 = 0; k0 < 256; k0 += 32) {
        short8 av = *(const short8*)&qs[l16 * 264 + k0 + kq];
#pragma unroll
        for (int ct = 0; ct < 4; ++ct) {
            int n = w * 64 + ct * 16 + l16;
            short8 bv = *(const short8*)&w2t[(size_t)n * 256 + k0 + kq];
            acc2[ct] = __builtin_amdgcn_mfma_f32_16x16x32_bf16(av, bv, acc2[ct], 0, 0, 0);
        }
    }
    __syncthreads();                      // done reading sm (GEMM1 result)
#pragma unroll
    for (int ct = 0; ct < 4; ++ct) {
        int n = w * 64 + ct * 16 + l16;
        float bias = b2[n];
#pragma unroll
        for (int r = 0; r < 4; ++r)
            sm[(rbase + r) * 260 + n] = acc2[ct][r] + bias;
    }
    __syncthreads();
    // ---- Poincare project -> qb8 (fp8), x2q
    {
        const int row = t >> 4, sub = t & 15;
        float s2 = 0.f;
#pragma unroll
        for (int i = 0; i < 16; ++i) {
            float v = sm[row * 260 + sub + 16 * i];
            s2 += v * v;
        }
#pragma unroll
        for (int off = 8; off; off >>= 1) s2 += __shfl_xor(s2, off, 16);
        float norm = sqrtf(s2);
        float scale = (norm > MAXN) ? MAXN / fmaxf(norm, EPSV) : 1.0f;
        if (sub == 0) x2q[q0 + row] = s2 * scale * scale;
#pragma unroll
        for (int i = 0; i < 16; ++i) {
            int cc = sub + 16 * i;
            qb8[(size_t)(q0 + row) * 256 + cc] = f2fp8(sm[row * 260 + cc] * scale);
        }
    }
}

// ---------------- main: wave-private pipelines, widened waves, BRANCHLESS epilogue ----
// Round-9-verified structure (wave owns 32 m-cols/tile, 16 MFMA per chain, zero loop
// barriers, grid 512 = 2 blocks/CU). SINGLE change: the candidate epilogue's 32 per-value
// branch pairs (wave-uniform if(mask) + divergent if(hit): SALU cmp + s_cbranch + saveexec
// round-trips, invisible to MfmaUtil/VALUBusy — the round-9 scaling data shows per-VALUE
// cost dominates) are replaced by a fully BRANCHLESS sequence: unconditional ballot+mbcnt
// prefix, slot = hit&&fit ? pos : TRASH, unconditional ds_write (misses collapse into a
// per-wave trash slot; same-address writes merge), scalar wcnt += popcount. Cap semantics
// identical to the verified rounds (hits beyond LCAPW dropped).
__global__ __launch_bounds__(256, 2) void k_dist(const u8* __restrict__ qb8,
                                                 const u8* __restrict__ mbf8,
                                                 u32* __restrict__ cnt,
                                                 uint2* __restrict__ cand) {
    __shared__ __align__(16) u8 ring[65536];   // wave w: [w*16384, +16384), 2 bufs x 8KB
    __shared__ uint2 candW[4 * (LCAPW + 1)];   // per-wave regions + trash slot at LCAPW
    __shared__ u32 wcntS[4];
    const int b = blockIdx.x;
    const int xcd = b & 7;
    const int idx = b >> 3;               // 0..63
    const int qt = idx >> 1;              // 0..31
    const int mg = xcd * 2 + (idx & 1);   // 0..15
    const int q0 = qt * 64;
    const int m0 = mg * 4096;
    const int t = threadIdx.x;
    const int w = t >> 6, lane = t & 63;
    const int l16 = lane & 15, Q = lane >> 4, rbase = Q * 4;

    // ---- prologue: stage A-panel (64 rows x 256B fp8 = 16KB) into ring[0..16383]
#pragma unroll
    for (int j = 0; j < 4; ++j) {
        int s = j * 256 + t;              // 16B slot 0..1023
        int r = s >> 4, p = s & 15;
        int c = p ^ (r & 15);
        gl2lds16(qb8 + (size_t)(q0 + r) * 256 + c * 16, ring + s * 16);
    }
    __syncthreads();                      // A resident (vmcnt 0 drained)

    // ---- lift A fragments into registers (held across the whole m-loop)
    i32x8 av[4][2];
#pragma unroll
    for (int i = 0; i < 4; ++i) {
        int R = i * 16 + l16;
        int aoff = R * 256 + (((Q * 2) ^ l16) << 4);
#pragma unroll
        for (int st = 0; st < 2; ++st) {
            i32x4 lo = *(const i32x4*)(ring + (aoff ^ (st << 7)));
            i32x4 hi = *(const i32x4*)(ring + (aoff ^ (st << 7) ^ 16));
            av[i][st] = __builtin_shufflevector(lo, hi, 0, 1, 2, 3, 4, 5, 6, 7);
        }
    }
    __syncthreads();                      // av reads drained (lgkmcnt 0); ring free for B

    // ---- per-wave B staging descriptors: instr i covers rows i*4..i*4+4 of wave's 32 rows
    const int rl = (lane >> 4);           // 0..3 row-within-instr
    const int pch = lane & 15;            // phys chunk
    const u8* pB[8];
#pragma unroll
    for (int i = 0; i < 8; ++i) {
        int rr = i * 4 + rl;              // 0..31 row within wave slice
        int c = pch ^ (rr & 15);          // source chunk (bijective key = row&15)
        pB[i] = mbf8 + (size_t)(m0 + w * 32 + rr) * 256 + c * 16;
    }
    u8* const wring = ring + w * 16384;
    const int ldst = lane * 16;           // lane x 16B within each 1KB instr segment

    // stage B tiles 0 (buf0) and 1 (buf1); tile stride = 128 cols * 256B = 32768
#pragma unroll
    for (int i = 0; i < 8; ++i) gl2lds16(pB[i], wring + i * 1024 + ldst);
#pragma unroll
    for (int i = 0; i < 8; ++i) gl2lds16(pB[i] + 32768, wring + 8192 + i * 1024 + ldst);

    // compute-side B offsets within wave buffer: col-fragment c covers rows c*16..c*16+16
    const int boff0 = l16 * 256 + (((Q * 2) ^ l16) << 4);
    const int boff1 = boff0 + 4096;

    f32x4 zero = {0.f, 0.f, 0.f, 0.f};
    u32 wcnt = 0;
    const u32 mgbase = (u32)(m0 + w * 32 + l16);
    uint2* const candMy = candW + w * (LCAPW + 1);
    const unsigned long long lmask_lt = (lane == 63) ? 0x7FFFFFFFFFFFFFFFull
                                                     : ((1ull << lane) - 1ull);

#pragma unroll 1
    for (int mt = 0; mt < 32; ++mt) {
        if (mt < 31) { asm volatile("s_waitcnt vmcnt(8)" ::: "memory"); }
        else         { asm volatile("s_waitcnt vmcnt(0)" ::: "memory"); }
        const u8* bufp = wring + ((mt & 1) << 13);
        // read bv for both k-halves x both col-fragments (8 x ds_read_b128)
        i32x4 a00 = *(const i32x4*)(bufp + boff0);
        i32x4 a01 = *(const i32x4*)(bufp + (boff0 ^ 16));
        i32x4 a10 = *(const i32x4*)(bufp + (boff0 ^ 128));
        i32x4 a11 = *(const i32x4*)(bufp + (boff0 ^ 128 ^ 16));
        i32x4 c00 = *(const i32x4*)(bufp + boff1);
        i32x4 c01 = *(const i32x4*)(bufp + (boff1 ^ 16));
        i32x4 c10 = *(const i32x4*)(bufp + (boff1 ^ 128));
        i32x4 c11 = *(const i32x4*)(bufp + (boff1 ^ 128 ^ 16));
        asm volatile("s_waitcnt lgkmcnt(0)" ::: "memory");   // reads done before buffer reuse
        __builtin_amdgcn_sched_barrier(0);
        if (mt < 30) {                    // stage tile mt+2 into this same (now-free) buffer
            const size_t so = (size_t)(mt + 2) * 32768;
            u8* d = (u8*)bufp;
#pragma unroll
            for (int i = 0; i < 8; ++i) gl2lds16(pB[i] + so, d + i * 1024 + ldst);
        }
        i32x8 bv00 = __builtin_shufflevector(a00, a01, 0, 1, 2, 3, 4, 5, 6, 7);  // st0, col-frag0
        i32x8 bv10 = __builtin_shufflevector(a10, a11, 0, 1, 2, 3, 4, 5, 6, 7);  // st1, col-frag0
        i32x8 bv01 = __builtin_shufflevector(c00, c01, 0, 1, 2, 3, 4, 5, 6, 7);  // st0, col-frag1
        i32x8 bv11 = __builtin_shufflevector(c10, c11, 0, 1, 2, 3, 4, 5, 6, 7);  // st1, col-frag1
        f32x4 acc[4][2];
#pragma unroll
        for (int i = 0; i < 4; ++i) { acc[i][0] = zero; acc[i][1] = zero; }
#pragma unroll
        for (int i = 0; i < 4; ++i) {
            acc[i][0] = __builtin_amdgcn_mfma_scale_f32_16x16x128_f8f6f4(
                av[i][0], bv00, acc[i][0], 0, 0, 0, 0x7F7F7F7F, 0, 0x7F7F7F7F);
            acc[i][1] = __builtin_amdgcn_mfma_scale_f32_16x16x128_f8f6f4(
                av[i][0], bv01, acc[i][1], 0, 0, 0, 0x7F7F7F7F, 0, 0x7F7F7F7F);
        }
#pragma unroll
        for (int i = 0; i < 4; ++i) {
            acc[i][0] = __builtin_amdgcn_mfma_scale_f32_16x16x128_f8f6f4(
                av[i][1], bv10, acc[i][0], 0, 0, 0, 0x7F7F7F7F, 0, 0x7F7F7F7F);
            acc[i][1] = __builtin_amdgcn_mfma_scale_f32_16x16x128_f8f6f4(
                av[i][1], bv11, acc[i][1], 0, 0, 0, 0x7F7F7F7F, 0, 0x7F7F7F7F);
        }
        // epilogue: BRANCHLESS candidate append (unconditional store, trash slot for misses)
        const u32 mglob = mgbase + (u32)(mt * 128);
#pragma unroll
        for (int i = 0; i < 4; ++i)
#pragma unroll
            for (int cf = 0; cf < 2; ++cf)
#pragma unroll
                for (int r = 0; r < 4; ++r) {
                    float d = acc[i][cf][r];
                    bool hit = d > THETA;
                    unsigned long long mask = __ballot(hit);
                    u32 pos = wcnt + (u32)__popcll(mask & lmask_lt);
                    u32 slot = (hit && pos < LCAPW) ? pos : LCAPW;
                    candMy[slot] = make_uint2(((u32)(i * 16 + rbase + r) << 16) |
                                              (mglob + (u32)(cf * 16)),
                                              __float_as_uint(d));
                    wcnt += (u32)__popcll(mask);
                }
    }

    if (lane == 0) wcntS[w] = wcnt;
    __syncthreads();
    // ---- flush all wave regions to global (trash slot never flushed)
#pragma unroll 1
    for (int wv = 0; wv < 4; ++wv) {
        u32 n = wcntS[wv]; if (n > LCAPW) n = LCAPW;
        for (u32 i = (u32)t; i < n; i += 256u) {
            uint2 e = candW[wv * (LCAPW + 1) + i];
            int q = q0 + (int)(e.x >> 16);
            u32 pos = atomicAdd(&cnt[q], 1u);
            if (pos < CAP) cand[(size_t)q * CAP + pos] = make_uint2(e.x & 0xFFFFu, e.y);
        }
    }
}

// ---------------- merge: exact top-16, softmax(-dist), weighted gather -> rb bf16 ----------------
__global__ __launch_bounds__(64, 4) void k_merge(const u32* __restrict__ cnt,
                                                 const uint2* __restrict__ cand,
                                                 const float* __restrict__ x2q,
                                                 const float* __restrict__ y2m,
                                                 const u16* __restrict__ mbf,
                                                 u16* __restrict__ rb) {
    const int q = blockIdx.x;
    const int lane = threadIdx.x;
    int n = (int)cnt[q]; if (n > CAP) n = CAP;
    const float x2 = x2q[q];
    const float dx = 1.0f - x2;
    float rv[8]; u32 mi[8];
#pragma unroll
    for (int j = 0; j < 8; ++j) {
        int idx = lane + 64 * j;
        rv[j] = 3.0e38f; mi[j] = 0;
        if (idx < n) {
            uint2 c = cand[(size_t)q * CAP + idx];
            float dot = __uint_as_float(c.y);
            float y2 = y2m[c.x];
            float sq = fmaxf(x2 + y2 - 2.0f * dot, 0.0f);
            float den = fmaxf(dx * (1.0f - y2), EPSV);
            rv[j] = sq / den;
            mi[j] = c.x;
        }
    }
    __shared__ float sdist[16];
    __shared__ u32 smi[16];
    __shared__ float swt[16];
    for (int k = 0; k < 16; ++k) {
        float lm = rv[0]; int ls = 0;
#pragma unroll
        for (int j = 1; j < 8; ++j) if (rv[j] < lm) { lm = rv[j]; ls = j; }
        unsigned long long key = (((unsigned long long)__float_as_uint(lm)) << 32) | (u32)(lane * 8 + ls);
#pragma unroll
        for (int off = 32; off; off >>= 1) {
            unsigned long long o = __shfl_xor(key, off);
            key = (o < key) ? o : key;
        }
        u32 sid = (u32)(key & 0xffffffffu);
        int wl = (int)(sid >> 3), wslot = (int)(sid & 7);
        if (lane == wl) {
            sdist[k] = rv[wslot];
            smi[k] = mi[wslot];
            rv[wslot] = 3.0e38f;
        }
    }
    __syncthreads();
    float rr = sdist[lane & 15];
    float arg = fmaxf(fmaf(2.0f, rr, 1.0f), 1.0f + EPSV);
    float dneg = -acoshf(arg);
    float mx = dneg;
#pragma unroll
    for (int off = 8; off; off >>= 1) mx = fmaxf(mx, __shfl_xor(mx, off, 16));
    float e = expf(dneg - mx);
    float ssum = e;
#pragma unroll
    for (int off = 8; off; off >>= 1) ssum += __shfl_xor(ssum, off, 16);
    if (lane < 16) swt[lane] = e / ssum;
    __syncthreads();
    float acc[4] = {0.f, 0.f, 0.f, 0.f};
    for (int k = 0; k < 16; ++k) {
        float wk = swt[k];
        const u16* mr = mbf + (size_t)smi[k] * 256;
#pragma unroll
        for (int j = 0; j < 4; ++j) acc[j] += wk * bf2f(mr[lane + 64 * j]);
    }
#pragma unroll
    for (int j = 0; j < 4; ++j) rb[(size_t)q * 256 + lane + 64 * j] = f2bf(acc[j]);
}

// ---------------- output: out = hidden + 0.1*(rb @ wp + bp) ----------------
__global__ __launch_bounds__(256) void k_out(const u16* __restrict__ rb,
                                             const u16* __restrict__ wpt,
                                             const float* __restrict__ bp,
                                             const float* __restrict__ hidden,
                                             float* __restrict__ out) {
    const int b = blockIdx.x;
    const int mt = b & 31, nt = b >> 5;
    const int t = threadIdx.x;
    const int w = t >> 6, lane = t & 63;
    const int l16 = lane & 15, kq = (lane >> 4) * 8, rbase = (lane >> 4) * 4;
    const int n = nt * 64 + w * 16 + l16;
    f32x4 zero = {0.f, 0.f, 0.f, 0.f};
    f32x4 acc[4] = {zero, zero, zero, zero};
    for (int k0 = 0; k0 < 256; k0 += 32) {
        short8 bv = *(const short8*)&wpt[(size_t)n * 256 + k0 + kq];
#pragma unroll
        for (int rt = 0; rt < 4; ++rt) {
            short8 av = *(const short8*)&rb[(size_t)(mt * 64 + rt * 16 + l16) * 256 + k0 + kq];
            acc[rt] = __builtin_amdgcn_mfma_f32_16x16x32_bf16(av, bv, acc[rt], 0, 0, 0);
        }
    }
    float bpn = bp[n];
#pragma unroll
    for (int rt = 0; rt < 4; ++rt)
#pragma unroll
        for (int r = 0; r < 4; ++r) {
            int m = mt * 64 + rt * 16 + rbase + r;
            out[(size_t)m * 1024 + n] = hidden[(size_t)m * 1024 + n] + 0.1f * (acc[rt][r] + bpn);
        }
}

extern "C" void kernel_launch(void* const* d_in, const int* in_sizes, int n_in,
                              void* d_out, int out_size, void* d_ws, size_t ws_size,
                              hipStream_t stream) {
    const float* hidden = (const float*)d_in[0];
    const float* memory = (const float*)d_in[1];
    const float* w1 = (const float*)d_in[2];
    const float* b1 = (const float*)d_in[3];
    const float* ln_g = (const float*)d_in[4];
    const float* ln_b = (const float*)d_in[5];
    const float* w2 = (const float*)d_in[6];
    const float* b2 = (const float*)d_in[7];
    const float* wp = (const float*)d_in[8];
    const float* bp = (const float*)d_in[9];
    float* out = (float*)d_out;
    char* ws = (char*)d_ws;

    u16* mbf  = (u16*)(ws);                       // 33554432
    float* y2m = (float*)(ws + 33554432);         // 262144
    u16* hb   = (u16*)(ws + 33816576);            // 4194304
    u16* w1t  = (u16*)(ws + 38010880);            // 524288
    u16* w2t  = (u16*)(ws + 38535168);            // 131072
    u16* wpt  = (u16*)(ws + 38666240);            // 524288
    u8*  qb8  = (u8*)(ws + 40239104);             // 524288 (in old qbb slot)
    float* x2q = (float*)(ws + 41287680);         // 8192
    u32* cnt  = (u32*)(ws + 41295872);            // 8192
    uint2* cand = (uint2*)(ws + 41304064);        // 8388608
    u16* rb   = (u16*)(ws + 49692672);            // 1048576
    u8*  mbf8 = (u8*)(ws + 50741248);             // 16777216 -> end 67518464

    hipLaunchKernelGGL(k_pre, dim3(18576), dim3(256), 0, stream,
                       memory, mbf, mbf8, y2m, cnt, hidden, hb, w1, w1t, w2, w2t, wp, wpt);
    hipLaunchKernelGGL(k_qnet, dim3(128), dim3(256), 0, stream,
                       hb, w1t, b1, ln_g, ln_b, w2t, b2, qb8, x2q);
    hipLaunchKernelGGL(k_dist, dim3(512), dim3(256), 0, stream, qb8, mbf8, cnt, cand);
    hipLaunchKernelGGL(k_merge, dim3(2048), dim3(64), 0, stream, cnt, cand, x2q, y2m, mbf, rb);
    hipLaunchKernelGGL(k_out, dim3(512), dim3(256), 0, stream, rb, wpt, bp, hidden, out);
}

// Round 11
// 272.976 us; speedup vs baseline: 1.0607x; 1.0607x over previous
//
#include <hip/hip_runtime.h>
#include <hip/hip_bf16.h>

typedef unsigned int u32;
typedef unsigned short u16;
typedef unsigned char u8;
typedef __attribute__((ext_vector_type(8))) short short8;
typedef __attribute__((ext_vector_type(4))) float f32x4;
typedef __attribute__((ext_vector_type(4))) int i32x4;
typedef __attribute__((ext_vector_type(8))) int i32x8;

#define EPSV 1e-5f
#define MAXN (1.0f - 1e-5f)
#define THETA 0.17f
#define CAP 512
#define LCAPW 384u

__device__ __forceinline__ u16 f2bf(float f) {
    union { float f; u32 u; } v; v.f = f;
    u32 u = v.u;
    u32 r = (u + 0x7fffu + ((u >> 16) & 1u)) >> 16;
    return (u16)r;
}
__device__ __forceinline__ float bf2f(u16 h) {
    union { u32 u; float f; } v; v.u = ((u32)h) << 16;
    return v.f;
}
// 4 floats -> 4 OCP e4m3 bytes (gfx950 HW cvt)
__device__ __forceinline__ u32 pk_fp8x4(float a, float b, float c, float d) {
    int v = __builtin_amdgcn_cvt_pk_fp8_f32(a, b, 0, false);
    v = __builtin_amdgcn_cvt_pk_fp8_f32(c, d, v, true);
    return (u32)v;
}
__device__ __forceinline__ u8 f2fp8(float a) {
    return (u8)(__builtin_amdgcn_cvt_pk_fp8_f32(a, a, 0, false) & 0xFF);
}

typedef __attribute__((address_space(1))) const unsigned char gbuf_t;
typedef __attribute__((address_space(3))) unsigned char lbuf_t;
__device__ __forceinline__ void gl2lds16(const void* g, void* l) {
    __builtin_amdgcn_global_load_lds((gbuf_t*)g, (lbuf_t*)l, 16, 0, 0);
}

// ---------------- fused pre: memory project + bf16 + fp8 + hidden->bf16 + transposes ----------------
__global__ __launch_bounds__(256) void k_pre(const float* __restrict__ mem,
                                             u16* __restrict__ mbf,
                                             u8* __restrict__ mbf8,
                                             float* __restrict__ y2m,
                                             u32* __restrict__ cnt,
                                             const float* __restrict__ hidden, u16* __restrict__ hb,
                                             const float* __restrict__ w1, u16* __restrict__ w1t,
                                             const float* __restrict__ w2, u16* __restrict__ w2t,
                                             const float* __restrict__ wp, u16* __restrict__ wpt) {
    __shared__ float ld[64 * 65];
    const int b = blockIdx.x, t = threadIdx.x;
    if (b < 16384) {                      // memory bank: project + bf16 + fp8 + y2
        int zi = b * 256 + t;
        if (zi < 2048) cnt[zi] = 0;
        const int row = b * 4 + (t >> 6);
        const int lane = t & 63;
        const float4* p = (const float4*)(mem + (size_t)row * 256);
        float4 v = p[lane];
        float ss = v.x * v.x + v.y * v.y + v.z * v.z + v.w * v.w;
#pragma unroll
        for (int off = 32; off; off >>= 1) ss += __shfl_xor(ss, off);
        float norm = sqrtf(ss);
        float scale = (norm > MAXN) ? MAXN / fmaxf(norm, EPSV) : 1.0f;
        float x0 = v.x * scale, x1 = v.y * scale, x2 = v.z * scale, x3 = v.w * scale;
        ushort4 u;
        u.x = f2bf(x0); u.y = f2bf(x1); u.z = f2bf(x2); u.w = f2bf(x3);
        *(ushort4*)&mbf[(size_t)row * 256 + lane * 4] = u;
        *(u32*)&mbf8[(size_t)row * 256 + lane * 4] = pk_fp8x4(x0, x1, x2, x3);
        if (lane == 0) y2m[row] = ss * scale * scale;
    } else if (b < 18432) {               // hidden f32 -> bf16
        int i = (b - 16384) * 256 + t;
        float4 v = ((const float4*)hidden)[i];
        ushort4 u; u.x = f2bf(v.x); u.y = f2bf(v.y); u.z = f2bf(v.z); u.w = f2bf(v.w);
        ((ushort4*)hb)[i] = u;
    } else {                              // transpose f32 src[K][N] -> bf16 dst[N][K], 64x64 tiles
        const float* src; u16* dst; int K, N, tile;
        int bb = b - 18432;
        if (bb < 64)      { src = w1; dst = w1t; K = 1024; N = 256;  tile = bb; }
        else if (bb < 80) { src = w2; dst = w2t; K = 256;  N = 256;  tile = bb - 64; }
        else              { src = wp; dst = wpt; K = 256;  N = 1024; tile = bb - 80; }
        int ntn = N >> 6;
        int tk = (tile / ntn) * 64, tn = (tile - (tile / ntn) * ntn) * 64;
#pragma unroll
        for (int j = 0; j < 16; ++j) {
            int lin = j * 256 + t;
            int r = lin >> 6, c = lin & 63;
            ld[r * 65 + c] = src[(size_t)(tk + r) * N + tn + c];
        }
        __syncthreads();
#pragma unroll
        for (int j = 0; j < 16; ++j) {
            int lin = j * 256 + t;
            int c2 = lin >> 6, r2 = lin & 63;
            dst[(size_t)(tn + c2) * K + tk + r2] = f2bf(ld[r2 * 65 + c2]);
        }
    }
}

// ---------------- fused query net: GEMM1 + bias + LN + GELU (LDS) + GEMM2 + bias + project ----
// grid 128, block 256 (4 waves), 16 q-rows per block. Emits fp8 q (for k_dist) + f32 x2q.
__global__ __launch_bounds__(256) void k_qnet(const u16* __restrict__ hb,
                                              const u16* __restrict__ w1t,
                                              const float* __restrict__ b1,
                                              const float* __restrict__ lng,
                                              const float* __restrict__ lnb,
                                              const u16* __restrict__ w2t,
                                              const float* __restrict__ b2,
                                              u8* __restrict__ qb8,
                                              float* __restrict__ x2q) {
    __shared__ float sm[16 * 260];
    __shared__ u16 qs[16 * 264];
    const int t = threadIdx.x;
    const int w = t >> 6, lane = t & 63;
    const int l16 = lane & 15, kq = (lane >> 4) * 8, rbase = (lane >> 4) * 4;
    const int q0 = blockIdx.x * 16;
    f32x4 zero = {0.f, 0.f, 0.f, 0.f};

    // ---- GEMM1: 16 x 256 (K=1024)
    {
        f32x4 acc[4] = {zero, zero, zero, zero};
        const u16* ap = hb + (size_t)(q0 + l16) * 1024 + kq;
        for (int k0 = 0; k0 < 1024; k0 += 32) {
            short8 av = *(const short8*)(ap + k0);
#pragma unroll
            for (int ct = 0; ct < 4; ++ct) {
                int n = w * 64 + ct * 16 + l16;
                short8 bv = *(const short8*)&w1t[(size_t)n * 1024 + k0 + kq];
                acc[ct] = __builtin_amdgcn_mfma_f32_16x16x32_bf16(av, bv, acc[ct], 0, 0, 0);
            }
        }
#pragma unroll
        for (int ct = 0; ct < 4; ++ct) {
            int n = w * 64 + ct * 16 + l16;
            float bias = b1[n];
#pragma unroll
            for (int r = 0; r < 4; ++r)
                sm[(rbase + r) * 260 + n] = acc[ct][r] + bias;
        }
    }
    __syncthreads();
    // ---- LayerNorm + GELU -> qs (bf16 in LDS)
    {
        const int row = t >> 4, sub = t & 15;
        float s1 = 0.f, s2 = 0.f;
#pragma unroll
        for (int i = 0; i < 16; ++i) {
            float v = sm[row * 260 + sub + 16 * i];
            s1 += v; s2 += v * v;
        }
#pragma unroll
        for (int off = 8; off; off >>= 1) {
            s1 += __shfl_xor(s1, off, 16);
            s2 += __shfl_xor(s2, off, 16);
        }
        float mu = s1 * (1.0f / 256.0f);
        float var = s2 * (1.0f / 256.0f) - mu * mu;
        float rstd = rsqrtf(var + EPSV);
#pragma unroll
        for (int i = 0; i < 16; ++i) {
            int cc = sub + 16 * i;
            float v = sm[row * 260 + cc];
            float xn = (v - mu) * rstd * lng[cc] + lnb[cc];
            float ge = 0.5f * xn * (1.0f + erff(xn * 0.7071067811865475f));
            qs[row * 264 + cc] = f2bf(ge);
        }
    }
    __syncthreads();
    // ---- GEMM2: 16 x 256 (K=256), A from LDS qs
    f32x4 acc2[4] = {zero, zero, zero, zero};
    for (int k0 = 0; k0 < 256; k0 += 32) {
        short8 av = *(const short8*)&qs[l16 * 264 + k0 + kq];
#pragma unroll
        for (int ct = 0; ct < 4; ++ct) {
            int n = w * 64 + ct * 16 + l16;
            short8 bv = *(const short8*)&w2t[(size_t)n * 256 + k0 + kq];
            acc2[ct] = __builtin_amdgcn_mfma_f32_16x16x32_bf16(av, bv, acc2[ct], 0, 0, 0);
        }
    }
    __syncthreads();                      // done reading sm (GEMM1 result)
#pragma unroll
    for (int ct = 0; ct < 4; ++ct) {
        int n = w * 64 + ct * 16 + l16;
        float bias = b2[n];
#pragma unroll
        for (int r = 0; r < 4; ++r)
            sm[(rbase + r) * 260 + n] = acc2[ct][r] + bias;
    }
    __syncthreads();
    // ---- Poincare project -> qb8 (fp8), x2q
    {
        const int row = t >> 4, sub = t & 15;
        float s2 = 0.f;
#pragma unroll
        for (int i = 0; i < 16; ++i) {
            float v = sm[row * 260 + sub + 16 * i];
            s2 += v * v;
        }
#pragma unroll
        for (int off = 8; off; off >>= 1) s2 += __shfl_xor(s2, off, 16);
        float norm = sqrtf(s2);
        float scale = (norm > MAXN) ? MAXN / fmaxf(norm, EPSV) : 1.0f;
        if (sub == 0) x2q[q0 + row] = s2 * scale * scale;
#pragma unroll
        for (int i = 0; i < 16; ++i) {
            int cc = sub + 16 * i;
            qb8[(size_t)(q0 + row) * 256 + cc] = f2fp8(sm[row * 260 + cc] * scale);
        }
    }
}

// ---------------- main: wave-private pipelines, widened waves, MASK-BASED epilogue ----
// Round-9-verified structure (wave owns 32 m-cols/tile, 16 MFMA per chain, zero loop
// barriers, grid 512). SINGLE change vs round 9: the epilogue's 32 per-value ballots
// (each a VALU->SGPR->SALU hazard chain through the CU's single shared scalar unit,
// invisible to MfmaUtil/VALUBusy; round 10 showed per-value cost dominates) are replaced
// by: per-lane 32-bit hit MASK built with pure VALU (no cross-lane, no SALU), ONE
// divergent if(hm) per tile (~3.6/64 lanes taken), ONE LDS atomicAdd for slot allocation,
// and a short ffs-loop (~1-2 iters) extracting values via a static cndmask mux tree
// (no runtime register indexing). Candidate SET identical; order within candW differs
// (k_merge is order-independent); cap semantics preserved.
__global__ __launch_bounds__(256, 2) void k_dist(const u8* __restrict__ qb8,
                                                 const u8* __restrict__ mbf8,
                                                 u32* __restrict__ cnt,
                                                 uint2* __restrict__ cand) {
    __shared__ __align__(16) u8 ring[65536];   // wave w: [w*16384, +16384), 2 bufs x 8KB
    __shared__ uint2 candW[4 * LCAPW];         // per-wave candidate regions
    __shared__ u32 wcntL[4];
    const int b = blockIdx.x;
    const int xcd = b & 7;
    const int idx = b >> 3;               // 0..63
    const int qt = idx >> 1;              // 0..31
    const int mg = xcd * 2 + (idx & 1);   // 0..15
    const int q0 = qt * 64;
    const int m0 = mg * 4096;
    const int t = threadIdx.x;
    const int w = t >> 6, lane = t & 63;
    const int l16 = lane & 15, Q = lane >> 4, rbase = Q * 4;

    if (t < 4) wcntL[t] = 0;

    // ---- prologue: stage A-panel (64 rows x 256B fp8 = 16KB) into ring[0..16383]
#pragma unroll
    for (int j = 0; j < 4; ++j) {
        int s = j * 256 + t;              // 16B slot 0..1023
        int r = s >> 4, p = s & 15;
        int c = p ^ (r & 15);
        gl2lds16(qb8 + (size_t)(q0 + r) * 256 + c * 16, ring + s * 16);
    }
    __syncthreads();                      // A resident (vmcnt 0 drained); wcntL visible

    // ---- lift A fragments into registers (held across the whole m-loop)
    i32x8 av[4][2];
#pragma unroll
    for (int i = 0; i < 4; ++i) {
        int R = i * 16 + l16;
        int aoff = R * 256 + (((Q * 2) ^ l16) << 4);
#pragma unroll
        for (int st = 0; st < 2; ++st) {
            i32x4 lo = *(const i32x4*)(ring + (aoff ^ (st << 7)));
            i32x4 hi = *(const i32x4*)(ring + (aoff ^ (st << 7) ^ 16));
            av[i][st] = __builtin_shufflevector(lo, hi, 0, 1, 2, 3, 4, 5, 6, 7);
        }
    }
    __syncthreads();                      // av reads drained (lgkmcnt 0); ring free for B

    // ---- per-wave B staging descriptors: instr i covers rows i*4..i*4+4 of wave's 32 rows
    const int rl = (lane >> 4);           // 0..3 row-within-instr
    const int pch = lane & 15;            // phys chunk
    const u8* pB[8];
#pragma unroll
    for (int i = 0; i < 8; ++i) {
        int rr = i * 4 + rl;              // 0..31 row within wave slice
        int c = pch ^ (rr & 15);          // source chunk (bijective key = row&15)
        pB[i] = mbf8 + (size_t)(m0 + w * 32 + rr) * 256 + c * 16;
    }
    u8* const wring = ring + w * 16384;
    const int ldst = lane * 16;           // lane x 16B within each 1KB instr segment

    // stage B tiles 0 (buf0) and 1 (buf1); tile stride = 128 cols * 256B = 32768
#pragma unroll
    for (int i = 0; i < 8; ++i) gl2lds16(pB[i], wring + i * 1024 + ldst);
#pragma unroll
    for (int i = 0; i < 8; ++i) gl2lds16(pB[i] + 32768, wring + 8192 + i * 1024 + ldst);

    // compute-side B offsets within wave buffer: col-fragment c covers rows c*16..c*16+16
    const int boff0 = l16 * 256 + (((Q * 2) ^ l16) << 4);
    const int boff1 = boff0 + 4096;

    f32x4 zero = {0.f, 0.f, 0.f, 0.f};
    const u32 mgbase = (u32)(m0 + w * 32 + l16);
    uint2* const candMy = candW + w * LCAPW;

#pragma unroll 1
    for (int mt = 0; mt < 32; ++mt) {
        if (mt < 31) { asm volatile("s_waitcnt vmcnt(8)" ::: "memory"); }
        else         { asm volatile("s_waitcnt vmcnt(0)" ::: "memory"); }
        const u8* bufp = wring + ((mt & 1) << 13);
        // read bv for both k-halves x both col-fragments (8 x ds_read_b128)
        i32x4 a00 = *(const i32x4*)(bufp + boff0);
        i32x4 a01 = *(const i32x4*)(bufp + (boff0 ^ 16));
        i32x4 a10 = *(const i32x4*)(bufp + (boff0 ^ 128));
        i32x4 a11 = *(const i32x4*)(bufp + (boff0 ^ 128 ^ 16));
        i32x4 c00 = *(const i32x4*)(bufp + boff1);
        i32x4 c01 = *(const i32x4*)(bufp + (boff1 ^ 16));
        i32x4 c10 = *(const i32x4*)(bufp + (boff1 ^ 128));
        i32x4 c11 = *(const i32x4*)(bufp + (boff1 ^ 128 ^ 16));
        asm volatile("s_waitcnt lgkmcnt(0)" ::: "memory");   // reads done before buffer reuse
        __builtin_amdgcn_sched_barrier(0);
        if (mt < 30) {                    // stage tile mt+2 into this same (now-free) buffer
            const size_t so = (size_t)(mt + 2) * 32768;
            u8* d = (u8*)bufp;
#pragma unroll
            for (int i = 0; i < 8; ++i) gl2lds16(pB[i] + so, d + i * 1024 + ldst);
        }
        i32x8 bv00 = __builtin_shufflevector(a00, a01, 0, 1, 2, 3, 4, 5, 6, 7);  // st0, col-frag0
        i32x8 bv10 = __builtin_shufflevector(a10, a11, 0, 1, 2, 3, 4, 5, 6, 7);  // st1, col-frag0
        i32x8 bv01 = __builtin_shufflevector(c00, c01, 0, 1, 2, 3, 4, 5, 6, 7);  // st0, col-frag1
        i32x8 bv11 = __builtin_shufflevector(c10, c11, 0, 1, 2, 3, 4, 5, 6, 7);  // st1, col-frag1
        f32x4 acc[4][2];
#pragma unroll
        for (int i = 0; i < 4; ++i) { acc[i][0] = zero; acc[i][1] = zero; }
#pragma unroll
        for (int i = 0; i < 4; ++i) {
            acc[i][0] = __builtin_amdgcn_mfma_scale_f32_16x16x128_f8f6f4(
                av[i][0], bv00, acc[i][0], 0, 0, 0, 0x7F7F7F7F, 0, 0x7F7F7F7F);
            acc[i][1] = __builtin_amdgcn_mfma_scale_f32_16x16x128_f8f6f4(
                av[i][0], bv01, acc[i][1], 0, 0, 0, 0x7F7F7F7F, 0, 0x7F7F7F7F);
        }
#pragma unroll
        for (int i = 0; i < 4; ++i) {
            acc[i][0] = __builtin_amdgcn_mfma_scale_f32_16x16x128_f8f6f4(
                av[i][1], bv10, acc[i][0], 0, 0, 0, 0x7F7F7F7F, 0, 0x7F7F7F7F);
            acc[i][1] = __builtin_amdgcn_mfma_scale_f32_16x16x128_f8f6f4(
                av[i][1], bv11, acc[i][1], 0, 0, 0, 0x7F7F7F7F, 0, 0x7F7F7F7F);
        }
        // ---- epilogue: per-lane hit mask (pure VALU), one branch + one LDS atomic per tile
        u32 hm = 0;
#pragma unroll
        for (int i = 0; i < 4; ++i)
#pragma unroll
            for (int cf = 0; cf < 2; ++cf)
#pragma unroll
                for (int r = 0; r < 4; ++r)
                    hm |= (acc[i][cf][r] > THETA) ? (1u << ((i << 3) | (cf << 2) | r)) : 0u;
        if (hm) {
            u32 base = atomicAdd(&wcntL[w], (u32)__popc(hm));
            const u32 mglob = mgbase + (u32)(mt * 128);
            while (hm) {
                u32 j = (u32)__ffs((int)hm) - 1u;
                hm &= hm - 1u;
                // static mux tree: g = j>>2 selects f32x4 (g = (i<<1)|cf), j&3 selects elem
                u32 g = j >> 2;
                f32x4 t0 = (g & 1) ? acc[0][1] : acc[0][0];
                f32x4 t1 = (g & 1) ? acc[1][1] : acc[1][0];
                f32x4 t2 = (g & 1) ? acc[2][1] : acc[2][0];
                f32x4 t3 = (g & 1) ? acc[3][1] : acc[3][0];
                f32x4 u0 = (g & 2) ? t1 : t0;
                f32x4 u1 = (g & 2) ? t3 : t2;
                f32x4 vv = (g & 4) ? u1 : u0;
                float d = (j & 2) ? ((j & 1) ? vv[3] : vv[2]) : ((j & 1) ? vv[1] : vv[0]);
                u32 qrow = (j >> 3) * 16u + (u32)rbase + (j & 3u);
                u32 mcol = mglob + ((j >> 2) & 1u) * 16u;
                if (base < LCAPW)
                    candMy[base] = make_uint2((qrow << 16) | mcol, __float_as_uint(d));
                ++base;
            }
        }
    }

    __syncthreads();
    // ---- flush all wave regions to global
#pragma unroll 1
    for (int wv = 0; wv < 4; ++wv) {
        u32 n = wcntL[wv]; if (n > LCAPW) n = LCAPW;
        for (u32 i = (u32)t; i < n; i += 256u) {
            uint2 e = candW[wv * LCAPW + i];
            int q = q0 + (int)(e.x >> 16);
            u32 pos = atomicAdd(&cnt[q], 1u);
            if (pos < CAP) cand[(size_t)q * CAP + pos] = make_uint2(e.x & 0xFFFFu, e.y);
        }
    }
}

// ---------------- merge: exact top-16, softmax(-dist), weighted gather -> rb bf16 ----------------
__global__ __launch_bounds__(64, 4) void k_merge(const u32* __restrict__ cnt,
                                                 const uint2* __restrict__ cand,
                                                 const float* __restrict__ x2q,
                                                 const float* __restrict__ y2m,
                                                 const u16* __restrict__ mbf,
                                                 u16* __restrict__ rb) {
    const int q = blockIdx.x;
    const int lane = threadIdx.x;
    int n = (int)cnt[q]; if (n > CAP) n = CAP;
    const float x2 = x2q[q];
    const float dx = 1.0f - x2;
    float rv[8]; u32 mi[8];
#pragma unroll
    for (int j = 0; j < 8; ++j) {
        int idx = lane + 64 * j;
        rv[j] = 3.0e38f; mi[j] = 0;
        if (idx < n) {
            uint2 c = cand[(size_t)q * CAP + idx];
            float dot = __uint_as_float(c.y);
            float y2 = y2m[c.x];
            float sq = fmaxf(x2 + y2 - 2.0f * dot, 0.0f);
            float den = fmaxf(dx * (1.0f - y2), EPSV);
            rv[j] = sq / den;
            mi[j] = c.x;
        }
    }
    __shared__ float sdist[16];
    __shared__ u32 smi[16];
    __shared__ float swt[16];
    for (int k = 0; k < 16; ++k) {
        float lm = rv[0]; int ls = 0;
#pragma unroll
        for (int j = 1; j < 8; ++j) if (rv[j] < lm) { lm = rv[j]; ls = j; }
        unsigned long long key = (((unsigned long long)__float_as_uint(lm)) << 32) | (u32)(lane * 8 + ls);
#pragma unroll
        for (int off = 32; off; off >>= 1) {
            unsigned long long o = __shfl_xor(key, off);
            key = (o < key) ? o : key;
        }
        u32 sid = (u32)(key & 0xffffffffu);
        int wl = (int)(sid >> 3), wslot = (int)(sid & 7);
        if (lane == wl) {
            sdist[k] = rv[wslot];
            smi[k] = mi[wslot];
            rv[wslot] = 3.0e38f;
        }
    }
    __syncthreads();
    float rr = sdist[lane & 15];
    float arg = fmaxf(fmaf(2.0f, rr, 1.0f), 1.0f + EPSV);
    float dneg = -acoshf(arg);
    float mx = dneg;
#pragma unroll
    for (int off = 8; off; off >>= 1) mx = fmaxf(mx, __shfl_xor(mx, off, 16));
    float e = expf(dneg - mx);
    float ssum = e;
#pragma unroll
    for (int off = 8; off; off >>= 1) ssum += __shfl_xor(ssum, off, 16);
    if (lane < 16) swt[lane] = e / ssum;
    __syncthreads();
    float acc[4] = {0.f, 0.f, 0.f, 0.f};
    for (int k = 0; k < 16; ++k) {
        float wk = swt[k];
        const u16* mr = mbf + (size_t)smi[k] * 256;
#pragma unroll
        for (int j = 0; j < 4; ++j) acc[j] += wk * bf2f(mr[lane + 64 * j]);
    }
#pragma unroll
    for (int j = 0; j < 4; ++j) rb[(size_t)q * 256 + lane + 64 * j] = f2bf(acc[j]);
}

// ---------------- output: out = hidden + 0.1*(rb @ wp + bp) ----------------
__global__ __launch_bounds__(256) void k_out(const u16* __restrict__ rb,
                                             const u16* __restrict__ wpt,
                                             const float* __restrict__ bp,
                                             const float* __restrict__ hidden,
                                             float* __restrict__ out) {
    const int b = blockIdx.x;
    const int mt = b & 31, nt = b >> 5;
    const int t = threadIdx.x;
    const int w = t >> 6, lane = t & 63;
    const int l16 = lane & 15, kq = (lane >> 4) * 8, rbase = (lane >> 4) * 4;
    const int n = nt * 64 + w * 16 + l16;
    f32x4 zero = {0.f, 0.f, 0.f, 0.f};
    f32x4 acc[4] = {zero, zero, zero, zero};
    for (int k0 = 0; k0 < 256; k0 += 32) {
        short8 bv = *(const short8*)&wpt[(size_t)n * 256 + k0 + kq];
#pragma unroll
        for (int rt = 0; rt < 4; ++rt) {
            short8 av = *(const short8*)&rb[(size_t)(mt * 64 + rt * 16 + l16) * 256 + k0 + kq];
            acc[rt] = __builtin_amdgcn_mfma_f32_16x16x32_bf16(av, bv, acc[rt], 0, 0, 0);
        }
    }
    float bpn = bp[n];
#pragma unroll
    for (int rt = 0; rt < 4; ++rt)
#pragma unroll
        for (int r = 0; r < 4; ++r) {
            int m = mt * 64 + rt * 16 + rbase + r;
            out[(size_t)m * 1024 + n] = hidden[(size_t)m * 1024 + n] + 0.1f * (acc[rt][r] + bpn);
        }
}

extern "C" void kernel_launch(void* const* d_in, const int* in_sizes, int n_in,
                              void* d_out, int out_size, void* d_ws, size_t ws_size,
                              hipStream_t stream) {
    const float* hidden = (const float*)d_in[0];
    const float* memory = (const float*)d_in[1];
    const float* w1 = (const float*)d_in[2];
    const float* b1 = (const float*)d_in[3];
    const float* ln_g = (const float*)d_in[4];
    const float* ln_b = (const float*)d_in[5];
    const float* w2 = (const float*)d_in[6];
    const float* b2 = (const float*)d_in[7];
    const float* wp = (const float*)d_in[8];
    const float* bp = (const float*)d_in[9];
    float* out = (float*)d_out;
    char* ws = (char*)d_ws;

    u16* mbf  = (u16*)(ws);                       // 33554432
    float* y2m = (float*)(ws + 33554432);         // 262144
    u16* hb   = (u16*)(ws + 33816576);            // 4194304
    u16* w1t  = (u16*)(ws + 38010880);            // 524288
    u16* w2t  = (u16*)(ws + 38535168);            // 131072
    u16* wpt  = (u16*)(ws + 38666240);            // 524288
    u8*  qb8  = (u8*)(ws + 40239104);             // 524288 (in old qbb slot)
    float* x2q = (float*)(ws + 41287680);         // 8192
    u32* cnt  = (u32*)(ws + 41295872);            // 8192
    uint2* cand = (uint2*)(ws + 41304064);        // 8388608
    u16* rb   = (u16*)(ws + 49692672);            // 1048576
    u8*  mbf8 = (u8*)(ws + 50741248);             // 16777216 -> end 67518464

    hipLaunchKernelGGL(k_pre, dim3(18576), dim3(256), 0, stream,
                       memory, mbf, mbf8, y2m, cnt, hidden, hb, w1, w1t, w2, w2t, wp, wpt);
    hipLaunchKernelGGL(k_qnet, dim3(128), dim3(256), 0, stream,
                       hb, w1t, b1, ln_g, ln_b, w2t, b2, qb8, x2q);
    hipLaunchKernelGGL(k_dist, dim3(512), dim3(256), 0, stream, qb8, mbf8, cnt, cand);
    hipLaunchKernelGGL(k_merge, dim3(2048), dim3(64), 0, stream, cnt, cand, x2q, y2m, mbf, rb);
    hipLaunchKernelGGL(k_out, dim3(512), dim3(256), 0, stream, rb, wpt, bp, hidden, out);
}

// Round 12
// 260.952 us; speedup vs baseline: 1.1096x; 1.0461x over previous
//
#include <hip/hip_runtime.h>
#include <hip/hip_bf16.h>

typedef unsigned int u32;
typedef unsigned short u16;
typedef unsigned char u8;
typedef __attribute__((ext_vector_type(8))) short short8;
typedef __attribute__((ext_vector_type(4))) float f32x4;
typedef __attribute__((ext_vector_type(4))) int i32x4;
typedef __attribute__((ext_vector_type(8))) int i32x8;

#define EPSV 1e-5f
#define MAXN (1.0f - 1e-5f)
#define THETA 0.17f
#define CAP 512
#define LCAPW 384u

__device__ __forceinline__ u16 f2bf(float f) {
    union { float f; u32 u; } v; v.f = f;
    u32 u = v.u;
    u32 r = (u + 0x7fffu + ((u >> 16) & 1u)) >> 16;
    return (u16)r;
}
__device__ __forceinline__ float bf2f(u16 h) {
    union { u32 u; float f; } v; v.u = ((u32)h) << 16;
    return v.f;
}
// 4 floats -> 4 OCP e4m3 bytes (gfx950 HW cvt)
__device__ __forceinline__ u32 pk_fp8x4(float a, float b, float c, float d) {
    int v = __builtin_amdgcn_cvt_pk_fp8_f32(a, b, 0, false);
    v = __builtin_amdgcn_cvt_pk_fp8_f32(c, d, v, true);
    return (u32)v;
}
__device__ __forceinline__ u8 f2fp8(float a) {
    return (u8)(__builtin_amdgcn_cvt_pk_fp8_f32(a, a, 0, false) & 0xFF);
}

typedef __attribute__((address_space(1))) const unsigned char gbuf_t;
typedef __attribute__((address_space(3))) unsigned char lbuf_t;
__device__ __forceinline__ void gl2lds16(const void* g, void* l) {
    __builtin_amdgcn_global_load_lds((gbuf_t*)g, (lbuf_t*)l, 16, 0, 0);
}

// ---------------- fused pre: memory project (fp8 + scale only) + hidden->bf16 + transposes ----
// R12: the 32MB bf16 memory copy (mbf) is ELIMINATED -- k_merge now gathers from the raw f32
// memory (L3-resident) scaled by per-row scale_m (256KB). k_pre write traffic 48MB -> 16MB.
__global__ __launch_bounds__(256) void k_pre(const float* __restrict__ mem,
                                             u8* __restrict__ mbf8,
                                             float* __restrict__ scale_m,
                                             float* __restrict__ y2m,
                                             u32* __restrict__ cnt,
                                             const float* __restrict__ hidden, u16* __restrict__ hb,
                                             const float* __restrict__ w1, u16* __restrict__ w1t,
                                             const float* __restrict__ w2, u16* __restrict__ w2t,
                                             const float* __restrict__ wp, u16* __restrict__ wpt) {
    __shared__ float ld[64 * 65];
    const int b = blockIdx.x, t = threadIdx.x;
    if (b < 16384) {                      // memory bank: project -> fp8 + y2 + scale
        int zi = b * 256 + t;
        if (zi < 2048) cnt[zi] = 0;
        const int row = b * 4 + (t >> 6);
        const int lane = t & 63;
        const float4* p = (const float4*)(mem + (size_t)row * 256);
        float4 v = p[lane];
        float ss = v.x * v.x + v.y * v.y + v.z * v.z + v.w * v.w;
#pragma unroll
        for (int off = 32; off; off >>= 1) ss += __shfl_xor(ss, off);
        float norm = sqrtf(ss);
        float scale = (norm > MAXN) ? MAXN / fmaxf(norm, EPSV) : 1.0f;
        float x0 = v.x * scale, x1 = v.y * scale, x2 = v.z * scale, x3 = v.w * scale;
        *(u32*)&mbf8[(size_t)row * 256 + lane * 4] = pk_fp8x4(x0, x1, x2, x3);
        if (lane == 0) { y2m[row] = ss * scale * scale; scale_m[row] = scale; }
    } else if (b < 18432) {               // hidden f32 -> bf16
        int i = (b - 16384) * 256 + t;
        float4 v = ((const float4*)hidden)[i];
        ushort4 u; u.x = f2bf(v.x); u.y = f2bf(v.y); u.z = f2bf(v.z); u.w = f2bf(v.w);
        ((ushort4*)hb)[i] = u;
    } else {                              // transpose f32 src[K][N] -> bf16 dst[N][K], 64x64 tiles
        const float* src; u16* dst; int K, N, tile;
        int bb = b - 18432;
        if (bb < 64)      { src = w1; dst = w1t; K = 1024; N = 256;  tile = bb; }
        else if (bb < 80) { src = w2; dst = w2t; K = 256;  N = 256;  tile = bb - 64; }
        else              { src = wp; dst = wpt; K = 256;  N = 1024; tile = bb - 80; }
        int ntn = N >> 6;
        int tk = (tile / ntn) * 64, tn = (tile - (tile / ntn) * ntn) * 64;
#pragma unroll
        for (int j = 0; j < 16; ++j) {
            int lin = j * 256 + t;
            int r = lin >> 6, c = lin & 63;
            ld[r * 65 + c] = src[(size_t)(tk + r) * N + tn + c];
        }
        __syncthreads();
#pragma unroll
        for (int j = 0; j < 16; ++j) {
            int lin = j * 256 + t;
            int c2 = lin >> 6, r2 = lin & 63;
            dst[(size_t)(tn + c2) * K + tk + r2] = f2bf(ld[r2 * 65 + c2]);
        }
    }
}

// ---------------- fused query net: GEMM1 + bias + LN + GELU (LDS) + GEMM2 + bias + project ----
// grid 128, block 256 (4 waves), 16 q-rows per block. Emits fp8 q (for k_dist) + f32 x2q.
__global__ __launch_bounds__(256) void k_qnet(const u16* __restrict__ hb,
                                              const u16* __restrict__ w1t,
                                              const float* __restrict__ b1,
                                              const float* __restrict__ lng,
                                              const float* __restrict__ lnb,
                                              const u16* __restrict__ w2t,
                                              const float* __restrict__ b2,
                                              u8* __restrict__ qb8,
                                              float* __restrict__ x2q) {
    __shared__ float sm[16 * 260];
    __shared__ u16 qs[16 * 264];
    const int t = threadIdx.x;
    const int w = t >> 6, lane = t & 63;
    const int l16 = lane & 15, kq = (lane >> 4) * 8, rbase = (lane >> 4) * 4;
    const int q0 = blockIdx.x * 16;
    f32x4 zero = {0.f, 0.f, 0.f, 0.f};

    // ---- GEMM1: 16 x 256 (K=1024)
    {
        f32x4 acc[4] = {zero, zero, zero, zero};
        const u16* ap = hb + (size_t)(q0 + l16) * 1024 + kq;
        for (int k0 = 0; k0 < 1024; k0 += 32) {
            short8 av = *(const short8*)(ap + k0);
#pragma unroll
            for (int ct = 0; ct < 4; ++ct) {
                int n = w * 64 + ct * 16 + l16;
                short8 bv = *(const short8*)&w1t[(size_t)n * 1024 + k0 + kq];
                acc[ct] = __builtin_amdgcn_mfma_f32_16x16x32_bf16(av, bv, acc[ct], 0, 0, 0);
            }
        }
#pragma unroll
        for (int ct = 0; ct < 4; ++ct) {
            int n = w * 64 + ct * 16 + l16;
            float bias = b1[n];
#pragma unroll
            for (int r = 0; r < 4; ++r)
                sm[(rbase + r) * 260 + n] = acc[ct][r] + bias;
        }
    }
    __syncthreads();
    // ---- LayerNorm + GELU -> qs (bf16 in LDS)
    {
        const int row = t >> 4, sub = t & 15;
        float s1 = 0.f, s2 = 0.f;
#pragma unroll
        for (int i = 0; i < 16; ++i) {
            float v = sm[row * 260 + sub + 16 * i];
            s1 += v; s2 += v * v;
        }
#pragma unroll
        for (int off = 8; off; off >>= 1) {
            s1 += __shfl_xor(s1, off, 16);
            s2 += __shfl_xor(s2, off, 16);
        }
        float mu = s1 * (1.0f / 256.0f);
        float var = s2 * (1.0f / 256.0f) - mu * mu;
        float rstd = rsqrtf(var + EPSV);
#pragma unroll
        for (int i = 0; i < 16; ++i) {
            int cc = sub + 16 * i;
            float v = sm[row * 260 + cc];
            float xn = (v - mu) * rstd * lng[cc] + lnb[cc];
            float ge = 0.5f * xn * (1.0f + erff(xn * 0.7071067811865475f));
            qs[row * 264 + cc] = f2bf(ge);
        }
    }
    __syncthreads();
    // ---- GEMM2: 16 x 256 (K=256), A from LDS qs
    f32x4 acc2[4] = {zero, zero, zero, zero};
    for (int k0 = 0; k0 < 256; k0 += 32) {
        short8 av = *(const short8*)&qs[l16 * 264 + k0 + kq];
#pragma unroll
        for (int ct = 0; ct < 4; ++ct) {
            int n = w * 64 + ct * 16 + l16;
            short8 bv = *(const short8*)&w2t[(size_t)n * 256 + k0 + kq];
            acc2[ct] = __builtin_amdgcn_mfma_f32_16x16x32_bf16(av, bv, acc2[ct], 0, 0, 0);
        }
    }
    __syncthreads();                      // done reading sm (GEMM1 result)
#pragma unroll
    for (int ct = 0; ct < 4; ++ct) {
        int n = w * 64 + ct * 16 + l16;
        float bias = b2[n];
#pragma unroll
        for (int r = 0; r < 4; ++r)
            sm[(rbase + r) * 260 + n] = acc2[ct][r] + bias;
    }
    __syncthreads();
    // ---- Poincare project -> qb8 (fp8), x2q
    {
        const int row = t >> 4, sub = t & 15;
        float s2 = 0.f;
#pragma unroll
        for (int i = 0; i < 16; ++i) {
            float v = sm[row * 260 + sub + 16 * i];
            s2 += v * v;
        }
#pragma unroll
        for (int off = 8; off; off >>= 1) s2 += __shfl_xor(s2, off, 16);
        float norm = sqrtf(s2);
        float scale = (norm > MAXN) ? MAXN / fmaxf(norm, EPSV) : 1.0f;
        if (sub == 0) x2q[q0 + row] = s2 * scale * scale;
#pragma unroll
        for (int i = 0; i < 16; ++i) {
            int cc = sub + 16 * i;
            qb8[(size_t)(q0 + row) * 256 + cc] = f2fp8(sm[row * 260 + cc] * scale);
        }
    }
}

// ---------------- main: ROUND-9 VERBATIM (best measured: 81.0us, ballot epilogue) ----------
// Wave owns 32 m-cols/tile, 16 MFMA per chain, zero loop barriers, grid 512 = 2 blocks/CU.
// Epilogue rewrites (R10 branchless, R11 mask+atomic) both regressed; ballot version kept.
__global__ __launch_bounds__(256, 2) void k_dist(const u8* __restrict__ qb8,
                                                 const u8* __restrict__ mbf8,
                                                 u32* __restrict__ cnt,
                                                 uint2* __restrict__ cand) {
    __shared__ __align__(16) u8 ring[65536];   // wave w: [w*16384, +16384), 2 bufs x 8KB
    __shared__ uint2 candW[4 * LCAPW];         // per-wave candidate regions
    __shared__ u32 wcntS[4];
    const int b = blockIdx.x;
    const int xcd = b & 7;
    const int idx = b >> 3;               // 0..63
    const int qt = idx >> 1;              // 0..31
    const int mg = xcd * 2 + (idx & 1);   // 0..15
    const int q0 = qt * 64;
    const int m0 = mg * 4096;
    const int t = threadIdx.x;
    const int w = t >> 6, lane = t & 63;
    const int l16 = lane & 15, Q = lane >> 4, rbase = Q * 4;

    // ---- prologue: stage A-panel (64 rows x 256B fp8 = 16KB) into ring[0..16383]
#pragma unroll
    for (int j = 0; j < 4; ++j) {
        int s = j * 256 + t;              // 16B slot 0..1023
        int r = s >> 4, p = s & 15;
        int c = p ^ (r & 15);
        gl2lds16(qb8 + (size_t)(q0 + r) * 256 + c * 16, ring + s * 16);
    }
    __syncthreads();                      // A resident (vmcnt 0 drained)

    // ---- lift A fragments into registers (held across the whole m-loop)
    i32x8 av[4][2];
#pragma unroll
    for (int i = 0; i < 4; ++i) {
        int R = i * 16 + l16;
        int aoff = R * 256 + (((Q * 2) ^ l16) << 4);
#pragma unroll
        for (int st = 0; st < 2; ++st) {
            i32x4 lo = *(const i32x4*)(ring + (aoff ^ (st << 7)));
            i32x4 hi = *(const i32x4*)(ring + (aoff ^ (st << 7) ^ 16));
            av[i][st] = __builtin_shufflevector(lo, hi, 0, 1, 2, 3, 4, 5, 6, 7);
        }
    }
    __syncthreads();                      // av reads drained (lgkmcnt 0); ring free for B

    // ---- per-wave B staging descriptors: instr i covers rows i*4..i*4+4 of wave's 32 rows
    const int rl = (lane >> 4);           // 0..3 row-within-instr
    const int pch = lane & 15;            // phys chunk
    const u8* pB[8];
#pragma unroll
    for (int i = 0; i < 8; ++i) {
        int rr = i * 4 + rl;              // 0..31 row within wave slice
        int c = pch ^ (rr & 15);          // source chunk (bijective key = row&15)
        pB[i] = mbf8 + (size_t)(m0 + w * 32 + rr) * 256 + c * 16;
    }
    u8* const wring = ring + w * 16384;
    const int ldst = lane * 16;           // lane x 16B within each 1KB instr segment

    // stage B tiles 0 (buf0) and 1 (buf1); tile stride = 128 cols * 256B = 32768
#pragma unroll
    for (int i = 0; i < 8; ++i) gl2lds16(pB[i], wring + i * 1024 + ldst);
#pragma unroll
    for (int i = 0; i < 8; ++i) gl2lds16(pB[i] + 32768, wring + 8192 + i * 1024 + ldst);

    // compute-side B offsets within wave buffer: col-fragment c covers rows c*16..c*16+16
    const int boff0 = l16 * 256 + (((Q * 2) ^ l16) << 4);
    const int boff1 = boff0 + 4096;

    f32x4 zero = {0.f, 0.f, 0.f, 0.f};
    u32 wcnt = 0;
    const u32 mgbase = (u32)(m0 + w * 32 + l16);

#pragma unroll 1
    for (int mt = 0; mt < 32; ++mt) {
        if (mt < 31) { asm volatile("s_waitcnt vmcnt(8)" ::: "memory"); }
        else         { asm volatile("s_waitcnt vmcnt(0)" ::: "memory"); }
        const u8* bufp = wring + ((mt & 1) << 13);
        // read bv for both k-halves x both col-fragments (8 x ds_read_b128)
        i32x4 a00 = *(const i32x4*)(bufp + boff0);
        i32x4 a01 = *(const i32x4*)(bufp + (boff0 ^ 16));
        i32x4 a10 = *(const i32x4*)(bufp + (boff0 ^ 128));
        i32x4 a11 = *(const i32x4*)(bufp + (boff0 ^ 128 ^ 16));
        i32x4 c00 = *(const i32x4*)(bufp + boff1);
        i32x4 c01 = *(const i32x4*)(bufp + (boff1 ^ 16));
        i32x4 c10 = *(const i32x4*)(bufp + (boff1 ^ 128));
        i32x4 c11 = *(const i32x4*)(bufp + (boff1 ^ 128 ^ 16));
        asm volatile("s_waitcnt lgkmcnt(0)" ::: "memory");   // reads done before buffer reuse
        __builtin_amdgcn_sched_barrier(0);
        if (mt < 30) {                    // stage tile mt+2 into this same (now-free) buffer
            const size_t so = (size_t)(mt + 2) * 32768;
            u8* d = (u8*)bufp;
#pragma unroll
            for (int i = 0; i < 8; ++i) gl2lds16(pB[i] + so, d + i * 1024 + ldst);
        }
        i32x8 bv00 = __builtin_shufflevector(a00, a01, 0, 1, 2, 3, 4, 5, 6, 7);  // st0, col-frag0
        i32x8 bv10 = __builtin_shufflevector(a10, a11, 0, 1, 2, 3, 4, 5, 6, 7);  // st1, col-frag0
        i32x8 bv01 = __builtin_shufflevector(c00, c01, 0, 1, 2, 3, 4, 5, 6, 7);  // st0, col-frag1
        i32x8 bv11 = __builtin_shufflevector(c10, c11, 0, 1, 2, 3, 4, 5, 6, 7);  // st1, col-frag1
        f32x4 acc[4][2];
#pragma unroll
        for (int i = 0; i < 4; ++i) { acc[i][0] = zero; acc[i][1] = zero; }
#pragma unroll
        for (int i = 0; i < 4; ++i) {
            acc[i][0] = __builtin_amdgcn_mfma_scale_f32_16x16x128_f8f6f4(
                av[i][0], bv00, acc[i][0], 0, 0, 0, 0x7F7F7F7F, 0, 0x7F7F7F7F);
            acc[i][1] = __builtin_amdgcn_mfma_scale_f32_16x16x128_f8f6f4(
                av[i][0], bv01, acc[i][1], 0, 0, 0, 0x7F7F7F7F, 0, 0x7F7F7F7F);
        }
#pragma unroll
        for (int i = 0; i < 4; ++i) {
            acc[i][0] = __builtin_amdgcn_mfma_scale_f32_16x16x128_f8f6f4(
                av[i][1], bv10, acc[i][0], 0, 0, 0, 0x7F7F7F7F, 0, 0x7F7F7F7F);
            acc[i][1] = __builtin_amdgcn_mfma_scale_f32_16x16x128_f8f6f4(
                av[i][1], bv11, acc[i][1], 0, 0, 0, 0x7F7F7F7F, 0, 0x7F7F7F7F);
        }
        // epilogue: ballot-aggregated candidate append (no atomics, register counter)
        const u32 mglob = mgbase + (u32)(mt * 128);
#pragma unroll
        for (int i = 0; i < 4; ++i)
#pragma unroll
            for (int cf = 0; cf < 2; ++cf)
#pragma unroll
                for (int r = 0; r < 4; ++r) {
                    float d = acc[i][cf][r];
                    unsigned long long mask = __ballot(d > THETA);
                    if (mask) {
                        if (d > THETA) {
                            u32 pos = wcnt + (u32)__popcll(mask & ((1ull << lane) - 1ull));
                            if (pos < LCAPW)
                                candW[w * LCAPW + pos] =
                                    make_uint2(((u32)(i * 16 + rbase + r) << 16) |
                                               (mglob + (u32)(cf * 16)),
                                               __float_as_uint(d));
                        }
                        wcnt += (u32)__popcll(mask);
                    }
                }
    }

    if (lane == 0) wcntS[w] = wcnt;
    __syncthreads();
    // ---- flush all wave regions to global
#pragma unroll 1
    for (int wv = 0; wv < 4; ++wv) {
        u32 n = wcntS[wv]; if (n > LCAPW) n = LCAPW;
        for (u32 i = (u32)t; i < n; i += 256u) {
            uint2 e = candW[wv * LCAPW + i];
            int q = q0 + (int)(e.x >> 16);
            u32 pos = atomicAdd(&cnt[q], 1u);
            if (pos < CAP) cand[(size_t)q * CAP + pos] = make_uint2(e.x & 0xFFFFu, e.y);
        }
    }
}

// ---------------- merge: exact top-16, softmax(-dist), weighted gather from f32 memory ----
__global__ __launch_bounds__(64, 4) void k_merge(const u32* __restrict__ cnt,
                                                 const uint2* __restrict__ cand,
                                                 const float* __restrict__ x2q,
                                                 const float* __restrict__ y2m,
                                                 const float* __restrict__ scale_m,
                                                 const float* __restrict__ mem,
                                                 u16* __restrict__ rb) {
    const int q = blockIdx.x;
    const int lane = threadIdx.x;
    int n = (int)cnt[q]; if (n > CAP) n = CAP;
    const float x2 = x2q[q];
    const float dx = 1.0f - x2;
    float rv[8]; u32 mi[8];
#pragma unroll
    for (int j = 0; j < 8; ++j) {
        int idx = lane + 64 * j;
        rv[j] = 3.0e38f; mi[j] = 0;
        if (idx < n) {
            uint2 c = cand[(size_t)q * CAP + idx];
            float dot = __uint_as_float(c.y);
            float y2 = y2m[c.x];
            float sq = fmaxf(x2 + y2 - 2.0f * dot, 0.0f);
            float den = fmaxf(dx * (1.0f - y2), EPSV);
            rv[j] = sq / den;
            mi[j] = c.x;
        }
    }
    __shared__ float sdist[16];
    __shared__ u32 smi[16];
    __shared__ float swt[16];
    for (int k = 0; k < 16; ++k) {
        float lm = rv[0]; int ls = 0;
#pragma unroll
        for (int j = 1; j < 8; ++j) if (rv[j] < lm) { lm = rv[j]; ls = j; }
        unsigned long long key = (((unsigned long long)__float_as_uint(lm)) << 32) | (u32)(lane * 8 + ls);
#pragma unroll
        for (int off = 32; off; off >>= 1) {
            unsigned long long o = __shfl_xor(key, off);
            key = (o < key) ? o : key;
        }
        u32 sid = (u32)(key & 0xffffffffu);
        int wl = (int)(sid >> 3), wslot = (int)(sid & 7);
        if (lane == wl) {
            sdist[k] = rv[wslot];
            smi[k] = mi[wslot];
            rv[wslot] = 3.0e38f;
        }
    }
    __syncthreads();
    float rr = sdist[lane & 15];
    float arg = fmaxf(fmaf(2.0f, rr, 1.0f), 1.0f + EPSV);
    float dneg = -acoshf(arg);
    float mx = dneg;
#pragma unroll
    for (int off = 8; off; off >>= 1) mx = fmaxf(mx, __shfl_xor(mx, off, 16));
    float e = expf(dneg - mx);
    float ssum = e;
#pragma unroll
    for (int off = 8; off; off >>= 1) ssum += __shfl_xor(ssum, off, 16);
    if (lane < 16) swt[lane] = e / ssum;
    __syncthreads();
    float acc[4] = {0.f, 0.f, 0.f, 0.f};
    for (int k = 0; k < 16; ++k) {
        u32 row = smi[k];
        float wks = swt[k] * scale_m[row];           // softmax weight x projection scale
        const float* mr = mem + (size_t)row * 256;
#pragma unroll
        for (int j = 0; j < 4; ++j) acc[j] += wks * mr[lane + 64 * j];
    }
#pragma unroll
    for (int j = 0; j < 4; ++j) rb[(size_t)q * 256 + lane + 64 * j] = f2bf(acc[j]);
}

// ---------------- output: out = hidden + 0.1*(rb @ wp + bp) ----------------
__global__ __launch_bounds__(256) void k_out(const u16* __restrict__ rb,
                                             const u16* __restrict__ wpt,
                                             const float* __restrict__ bp,
                                             const float* __restrict__ hidden,
                                             float* __restrict__ out) {
    const int b = blockIdx.x;
    const int mt = b & 31, nt = b >> 5;
    const int t = threadIdx.x;
    const int w = t >> 6, lane = t & 63;
    const int l16 = lane & 15, kq = (lane >> 4) * 8, rbase = (lane >> 4) * 4;
    const int n = nt * 64 + w * 16 + l16;
    f32x4 zero = {0.f, 0.f, 0.f, 0.f};
    f32x4 acc[4] = {zero, zero, zero, zero};
    for (int k0 = 0; k0 < 256; k0 += 32) {
        short8 bv = *(const short8*)&wpt[(size_t)n * 256 + k0 + kq];
#pragma unroll
        for (int rt = 0; rt < 4; ++rt) {
            short8 av = *(const short8*)&rb[(size_t)(mt * 64 + rt * 16 + l16) * 256 + k0 + kq];
            acc[rt] = __builtin_amdgcn_mfma_f32_16x16x32_bf16(av, bv, acc[rt], 0, 0, 0);
        }
    }
    float bpn = bp[n];
#pragma unroll
    for (int rt = 0; rt < 4; ++rt)
#pragma unroll
        for (int r = 0; r < 4; ++r) {
            int m = mt * 64 + rt * 16 + rbase + r;
            out[(size_t)m * 1024 + n] = hidden[(size_t)m * 1024 + n] + 0.1f * (acc[rt][r] + bpn);
        }
}

extern "C" void kernel_launch(void* const* d_in, const int* in_sizes, int n_in,
                              void* d_out, int out_size, void* d_ws, size_t ws_size,
                              hipStream_t stream) {
    const float* hidden = (const float*)d_in[0];
    const float* memory = (const float*)d_in[1];
    const float* w1 = (const float*)d_in[2];
    const float* b1 = (const float*)d_in[3];
    const float* ln_g = (const float*)d_in[4];
    const float* ln_b = (const float*)d_in[5];
    const float* w2 = (const float*)d_in[6];
    const float* b2 = (const float*)d_in[7];
    const float* wp = (const float*)d_in[8];
    const float* bp = (const float*)d_in[9];
    float* out = (float*)d_out;
    char* ws = (char*)d_ws;

    float* scale_m = (float*)(ws);                // 262144 (old mbf slot)
    float* y2m = (float*)(ws + 33554432);         // 262144
    u16* hb   = (u16*)(ws + 33816576);            // 4194304
    u16* w1t  = (u16*)(ws + 38010880);            // 524288
    u16* w2t  = (u16*)(ws + 38535168);            // 131072
    u16* wpt  = (u16*)(ws + 38666240);            // 524288
    u8*  qb8  = (u8*)(ws + 40239104);             // 524288 (in old qbb slot)
    float* x2q = (float*)(ws + 41287680);         // 8192
    u32* cnt  = (u32*)(ws + 41295872);            // 8192
    uint2* cand = (uint2*)(ws + 41304064);        // 8388608
    u16* rb   = (u16*)(ws + 49692672);            // 1048576
    u8*  mbf8 = (u8*)(ws + 50741248);             // 16777216 -> end 67518464

    hipLaunchKernelGGL(k_pre, dim3(18576), dim3(256), 0, stream,
                       memory, mbf8, scale_m, y2m, cnt, hidden, hb, w1, w1t, w2, w2t, wp, wpt);
    hipLaunchKernelGGL(k_qnet, dim3(128), dim3(256), 0, stream,
                       hb, w1t, b1, ln_g, ln_b, w2t, b2, qb8, x2q);
    hipLaunchKernelGGL(k_dist, dim3(512), dim3(256), 0, stream, qb8, mbf8, cnt, cand);
    hipLaunchKernelGGL(k_merge, dim3(2048), dim3(64), 0, stream, cnt, cand, x2q, y2m, scale_m, memory, rb);
    hipLaunchKernelGGL(k_out, dim3(512), dim3(256), 0, stream, rb, wpt, bp, hidden, out);
}